// Round 1
// baseline (173.663 us; speedup 1.0000x reference)
//
#include <hip/hip_runtime.h>
#include <hip/hip_bf16.h>

// Skipgram negative-sampling loss on MI355X — round 10.
// R9: fp8 gather, 8 lanes/sample, ~90 VGPR -> allocates 128 -> 16 waves/CU.
// R10 theory: gather is latency-bound (poison-fill wipes L3 each iter; two
// dependent round-trips idx->row). Occupancy halves at VGPR=64/128/256 cliffs
// (m69). Restructure to 16 lanes/sample: r[11] uint2 (22 VGPR) + a 2xfloat4
// (8 VGPR) + 32-bit SADDR offsets -> target <=64 VGPR -> 32 waves/CU (2x).

#define N_SAMPLES 65536
#define N_DIMS 128
#define K_NEG 10
#define N_WORDS 100000
#define WOUT_FP8_BYTES ((size_t)N_WORDS * N_DIMS)   // 12.8 MB

__global__ void zero_out_kernel(float* out) {
    if (threadIdx.x == 0 && blockIdx.x == 0) out[0] = 0.0f;
}

__device__ __forceinline__ float log_sigmoid_fast(float x) {
    float ax = fabsf(x);
    return fminf(x, 0.0f) - __logf(1.0f + __expf(-ax));
}

__device__ __forceinline__ float dot4(float4 a, float4 b) {
    return a.x * b.x + a.y * b.y + a.z * b.z + a.w * b.w;
}

__device__ __forceinline__ float group8_reduce(float v) {
    v += __shfl_xor(v, 4);
    v += __shfl_xor(v, 2);
    v += __shfl_xor(v, 1);
    return v;
}

// ---- fp32 -> fp8 e4m3 (OCP) streaming conversion into d_ws ----------------
// One uint4 (16 fp8) per thread-iteration: 4x float4 in, 1x uint4 out.
__global__ __launch_bounds__(256) void convert_fp8_kernel(
        const float* __restrict__ W_out, uint4* __restrict__ dst,
        float* __restrict__ out)
{
    if (blockIdx.x == 0 && threadIdx.x == 0) out[0] = 0.0f;  // fold zero_out in
    const size_t total16 = (size_t)N_WORDS * N_DIMS / 16;    // 800000
    const size_t i = blockIdx.x * (size_t)blockDim.x + threadIdx.x;
    if (i >= total16) return;
    const float4* __restrict__ src = (const float4*)W_out;
    float4 f0 = src[4 * i + 0];
    float4 f1 = src[4 * i + 1];
    float4 f2 = src[4 * i + 2];
    float4 f3 = src[4 * i + 3];
    uint4 p;
    p.x = __builtin_amdgcn_cvt_pk_fp8_f32(f0.z, f0.w,
          __builtin_amdgcn_cvt_pk_fp8_f32(f0.x, f0.y, 0u, false), true);
    p.y = __builtin_amdgcn_cvt_pk_fp8_f32(f1.z, f1.w,
          __builtin_amdgcn_cvt_pk_fp8_f32(f1.x, f1.y, 0u, false), true);
    p.z = __builtin_amdgcn_cvt_pk_fp8_f32(f2.z, f2.w,
          __builtin_amdgcn_cvt_pk_fp8_f32(f2.x, f2.y, 0u, false), true);
    p.w = __builtin_amdgcn_cvt_pk_fp8_f32(f3.z, f3.w,
          __builtin_amdgcn_cvt_pk_fp8_f32(f3.x, f3.y, 0u, false), true);
    dst[i] = p;
}

// ---- fp8 word dot: 4 fp8 elems vs one float4 ------------------------------
__device__ __forceinline__ float dot_word_fp8(float4 a, unsigned int w, float acc) {
    auto p0 = __builtin_amdgcn_cvt_pk_f32_fp8(w, false);  // elements 0,1
    auto p1 = __builtin_amdgcn_cvt_pk_f32_fp8(w, true);   // elements 2,3
    acc = fmaf(a.x, p0[0], acc);
    acc = fmaf(a.y, p0[1], acc);
    acc = fmaf(a.z, p1[0], acc);
    acc = fmaf(a.w, p1[1], acc);
    return acc;
}

// ---- Gather kernel: 16 lanes/sample, uint2 row slices, <=64 VGPR target ----
// Lane g of a 16-lane group holds dims [8g..8g+7]: 2x float4 of W_in,
// 1x uint2 (8 fp8 bytes) per gathered row. 128B/row coalesced per group.
__global__ __launch_bounds__(256, 8) void skipgram_fp8_kernel(
        const int* __restrict__ input_idx,
        const int* __restrict__ output_idx,
        const int* __restrict__ neg_idx,
        const float* __restrict__ W_in,
        const unsigned char* __restrict__ Wo8,
        float* __restrict__ out)
{
    const int g = threadIdx.x & 15;                               // lane in group
    const int n = (blockIdx.x * blockDim.x + threadIdx.x) >> 4;   // sample id

    // All 12 indices up front. neg_idx base n*10 ints = 40n bytes: always
    // 8-aligned -> 5x int2 loads. (HW-broadcast within the 16-lane group.)
    int idx[12];
    idx[0] = input_idx[n];
    idx[1] = output_idx[n];
    const int2* __restrict__ np = (const int2*)(neg_idx + (size_t)n * K_NEG);
    #pragma unroll
    for (int k = 0; k < 5; ++k) {
        int2 v = np[k];
        idx[2 + 2 * k]     = v.x;
        idx[2 + 2 * k + 1] = v.y;
    }

    // Input row fp32: lane g holds dims [8g..8g+7] = float4 slots 2g, 2g+1.
    const float4* __restrict__ arow = (const float4*)(W_in + (size_t)idx[0] * N_DIMS);
    float4 a0 = arow[2 * g + 0];
    float4 a1 = arow[2 * g + 1];

    // 11 gathered fp8 rows: lane g reads bytes [8g..8g+7] = 1 x uint2.
    // 32-bit offsets (max 12.8M) -> SADDR-form loads, 1 VGPR per address.
    uint2 r[11];
    #pragma unroll
    for (int t = 0; t < 11; ++t) {
        const unsigned off = (unsigned)idx[1 + t] * (unsigned)N_DIMS + 8u * g;
        r[t] = *(const uint2*)(Wo8 + off);
    }

    // Pin: loads may not sink below this point.
    __builtin_amdgcn_sched_barrier(0);

    float acc = 0.0f;
    #pragma unroll
    for (int t = 0; t < 11; ++t) {
        float d = 0.0f;
        d = dot_word_fp8(a0, r[t].x, d);
        d = dot_word_fp8(a1, r[t].y, d);
        d += __shfl_xor(d, 8);
        d += __shfl_xor(d, 4);
        d += __shfl_xor(d, 2);
        d += __shfl_xor(d, 1);
        acc += log_sigmoid_fast(t == 0 ? d : -d);
    }

    __shared__ float sdata[16];
    if (g == 0) sdata[threadIdx.x >> 4] = acc;
    __syncthreads();
    if (threadIdx.x < 16) {
        float s = sdata[threadIdx.x];
        s += __shfl_xor(s, 8);
        s += __shfl_xor(s, 4);
        s += __shfl_xor(s, 2);
        s += __shfl_xor(s, 1);
        if (threadIdx.x == 0)
            atomicAdd(out, s * (1.0f / (float)N_SAMPLES));
    }
}

// ---- Fallback fp32 path (R5 kernel) in case ws_size < 12.8 MB -------------
__global__ __launch_bounds__(256, 2) void skipgram_f32_kernel(
        const int* __restrict__ input_idx,
        const int* __restrict__ output_idx,
        const int* __restrict__ neg_idx,
        const float* __restrict__ W_in,
        const float* __restrict__ W_out,
        float* __restrict__ out)
{
    const int g = threadIdx.x & 7;
    const int n = (blockIdx.x * blockDim.x + threadIdx.x) >> 3;

    int idx[12];
    idx[0] = input_idx[n];
    idx[1] = output_idx[n];
    #pragma unroll
    for (int k = 0; k < K_NEG; ++k) idx[2 + k] = neg_idx[n * K_NEG + k];

    const float4* __restrict__ arow = (const float4*)(W_in + (size_t)idx[0] * N_DIMS);
    float4 a0 = arow[0 * 8 + g];
    float4 a1 = arow[1 * 8 + g];
    float4 a2 = arow[2 * 8 + g];
    float4 a3 = arow[3 * 8 + g];

    float4 r[11][4];
    #pragma unroll
    for (int t = 0; t < 11; ++t) {
        const float4* __restrict__ rr =
            (const float4*)(W_out + (size_t)idx[1 + t] * N_DIMS);
        r[t][0] = rr[0 * 8 + g];
        r[t][1] = rr[1 * 8 + g];
        r[t][2] = rr[2 * 8 + g];
        r[t][3] = rr[3 * 8 + g];
    }
    __builtin_amdgcn_sched_barrier(0);

    float acc = 0.0f;
    #pragma unroll
    for (int t = 0; t < 11; ++t) {
        float d = dot4(a0, r[t][0]) + dot4(a1, r[t][1])
                + dot4(a2, r[t][2]) + dot4(a3, r[t][3]);
        d = group8_reduce(d);
        acc += log_sigmoid_fast(t == 0 ? d : -d);
    }

    __shared__ float sdata[32];
    if (g == 0) sdata[threadIdx.x >> 3] = acc;
    __syncthreads();
    if (threadIdx.x < 32) {
        float s = sdata[threadIdx.x];
        s += __shfl_xor(s, 16);
        s += __shfl_xor(s, 8);
        s += __shfl_xor(s, 4);
        s += __shfl_xor(s, 2);
        s += __shfl_xor(s, 1);
        if (threadIdx.x == 0)
            atomicAdd(out, s * (1.0f / (float)N_SAMPLES));
    }
}

extern "C" void kernel_launch(void* const* d_in, const int* in_sizes, int n_in,
                              void* d_out, int out_size, void* d_ws, size_t ws_size,
                              hipStream_t stream) {
    const int*   input_idx  = (const int*)d_in[0];
    const int*   output_idx = (const int*)d_in[1];
    const int*   neg_idx    = (const int*)d_in[2];
    const float* W_in       = (const float*)d_in[3];
    const float* W_out      = (const float*)d_in[4];
    float* out = (float*)d_out;

    if (ws_size >= WOUT_FP8_BYTES) {
        uint4* Wo8 = (uint4*)d_ws;
        const int ctotal = (int)((size_t)N_WORDS * N_DIMS / 16);  // 800000
        const int cgrid  = (ctotal + 255) / 256;                  // 3125
        convert_fp8_kernel<<<cgrid, 256, 0, stream>>>(W_out, Wo8, out);
        const int block = 256;                        // 16 groups of 16 lanes
        const int grid  = N_SAMPLES / (block / 16);   // 4096 blocks, exact cover
        skipgram_fp8_kernel<<<grid, block, 0, stream>>>(
            input_idx, output_idx, neg_idx, W_in,
            (const unsigned char*)Wo8, out);
    } else {
        zero_out_kernel<<<1, 64, 0, stream>>>(out);
        const int block = 256;
        const int grid  = N_SAMPLES / (block / 8);    // 2048 blocks
        skipgram_f32_kernel<<<grid, block, 0, stream>>>(
            input_idx, output_idx, neg_idx, W_in, W_out, out);
    }
}

// Round 2
// 148.643 us; speedup vs baseline: 1.1683x; 1.1683x over previous
//
#include <hip/hip_runtime.h>
#include <hip/hip_bf16.h>

// Skipgram negative-sampling loss on MI355X — round 11.
// R9 (148us total): 8-lane groups, uint4 fp8 rows, ~90 VGPR -> 4-5 waves/SIMD.
// R10 (FAILED, 174us): 16-lane + launch_bounds(256,8) -> compiler squeezed to
// 24 VGPR and SERIALIZED the 11-row load batch (MLP collapsed). Lesson:
// occupancy bought by shrinking the in-flight load set is a net loss.
// R11: revert to R9 structure; trim VGPR via 32-bit SADDR offsets (both
// tables < 52MB) and cap with launch_bounds(256,6) -> ~84 VGPR cap, live set
// ~70 fits the full 11-load batch -> 6 waves/SIMD (+50% MLP vs R9).

#define N_SAMPLES 65536
#define N_DIMS 128
#define K_NEG 10
#define N_WORDS 100000
#define WOUT_FP8_BYTES ((size_t)N_WORDS * N_DIMS)   // 12.8 MB

__global__ void zero_out_kernel(float* out) {
    if (threadIdx.x == 0 && blockIdx.x == 0) out[0] = 0.0f;
}

__device__ __forceinline__ float log_sigmoid_fast(float x) {
    float ax = fabsf(x);
    return fminf(x, 0.0f) - __logf(1.0f + __expf(-ax));
}

__device__ __forceinline__ float dot4(float4 a, float4 b) {
    return a.x * b.x + a.y * b.y + a.z * b.z + a.w * b.w;
}

__device__ __forceinline__ float group8_reduce(float v) {
    v += __shfl_xor(v, 4);
    v += __shfl_xor(v, 2);
    v += __shfl_xor(v, 1);
    return v;
}

// ---- fp32 -> fp8 e4m3 (OCP) streaming conversion into d_ws ----------------
// One uint4 (16 fp8) per thread-iteration: 4x float4 in, 1x uint4 out.
__global__ __launch_bounds__(256) void convert_fp8_kernel(
        const float* __restrict__ W_out, uint4* __restrict__ dst,
        float* __restrict__ out)
{
    if (blockIdx.x == 0 && threadIdx.x == 0) out[0] = 0.0f;  // fold zero_out in
    const size_t total16 = (size_t)N_WORDS * N_DIMS / 16;    // 800000
    const size_t i = blockIdx.x * (size_t)blockDim.x + threadIdx.x;
    if (i >= total16) return;
    const float4* __restrict__ src = (const float4*)W_out;
    float4 f0 = src[4 * i + 0];
    float4 f1 = src[4 * i + 1];
    float4 f2 = src[4 * i + 2];
    float4 f3 = src[4 * i + 3];
    uint4 p;
    p.x = __builtin_amdgcn_cvt_pk_fp8_f32(f0.z, f0.w,
          __builtin_amdgcn_cvt_pk_fp8_f32(f0.x, f0.y, 0u, false), true);
    p.y = __builtin_amdgcn_cvt_pk_fp8_f32(f1.z, f1.w,
          __builtin_amdgcn_cvt_pk_fp8_f32(f1.x, f1.y, 0u, false), true);
    p.z = __builtin_amdgcn_cvt_pk_fp8_f32(f2.z, f2.w,
          __builtin_amdgcn_cvt_pk_fp8_f32(f2.x, f2.y, 0u, false), true);
    p.w = __builtin_amdgcn_cvt_pk_fp8_f32(f3.z, f3.w,
          __builtin_amdgcn_cvt_pk_fp8_f32(f3.x, f3.y, 0u, false), true);
    dst[i] = p;
}

// ---- fp8 row dot: lane holds 16 fp8 (uint4) + 16 fp32 dims (4x float4) ----
__device__ __forceinline__ float dot_word_fp8(float4 a, unsigned int w, float acc) {
    auto p0 = __builtin_amdgcn_cvt_pk_f32_fp8(w, false);  // elements 0,1
    auto p1 = __builtin_amdgcn_cvt_pk_f32_fp8(w, true);   // elements 2,3
    acc = fmaf(a.x, p0[0], acc);
    acc = fmaf(a.y, p0[1], acc);
    acc = fmaf(a.z, p1[0], acc);
    acc = fmaf(a.w, p1[1], acc);
    return acc;
}

__device__ __forceinline__ float dot_row_fp8(const float4 a0, const float4 a1,
                                             const float4 a2, const float4 a3,
                                             const uint4 b) {
    float acc = 0.0f;
    acc = dot_word_fp8(a0, b.x, acc);
    acc = dot_word_fp8(a1, b.y, acc);
    acc = dot_word_fp8(a2, b.z, acc);
    acc = dot_word_fp8(a3, b.w, acc);
    return acc;
}

// ---- Gather kernel: 8 lanes/sample (R9 structure), 32-bit SADDR offsets ----
// Lane g holds dims [16g..16g+15]. Live set at the batch point ~70 VGPR:
// r[11] uint4 (44) + a0..a3 (16) + temps. launch_bounds(256,6) caps at ~84,
// leaving the full 11-load batch intact -> 6 waves/SIMD.
__global__ __launch_bounds__(256, 6) void skipgram_fp8_kernel(
        const int* __restrict__ input_idx,
        const int* __restrict__ output_idx,
        const int* __restrict__ neg_idx,
        const float* __restrict__ W_in,
        const unsigned char* __restrict__ Wo8,
        float* __restrict__ out)
{
    const int g = threadIdx.x & 7;                               // lane in group
    const int n = (blockIdx.x * blockDim.x + threadIdx.x) >> 3;  // sample id

    // All 12 indices up front. neg_idx base n*10 ints = 40n bytes: always
    // 8-aligned -> 5x int2 loads. (HW-broadcast within the 8-lane group.)
    int idx[12];
    idx[0] = input_idx[n];
    idx[1] = output_idx[n];
    const int2* __restrict__ np = (const int2*)(neg_idx + (size_t)n * K_NEG);
    #pragma unroll
    for (int k = 0; k < 5; ++k) {
        int2 v = np[k];
        idx[2 + 2 * k]     = v.x;
        idx[2 + 2 * k + 1] = v.y;
    }

    // Input row fp32: lane g holds dims [16g..16g+15] = byte off 64g..64g+63.
    // 32-bit offset (max 51.2MB) -> SADDR-form dwordx4 loads, 1 addr VGPR.
    const char* __restrict__ Wi8 = (const char*)W_in;
    const unsigned aoff = (unsigned)idx[0] * (unsigned)(N_DIMS * 4) + 64u * g;
    float4 a0 = *(const float4*)(Wi8 + aoff);
    float4 a1 = *(const float4*)(Wi8 + aoff + 16u);
    float4 a2 = *(const float4*)(Wi8 + aoff + 32u);
    float4 a3 = *(const float4*)(Wi8 + aoff + 48u);

    // 11 gathered fp8 rows: lane g reads bytes [16g..16g+15] = 1 x uint4.
    // 32-bit offsets (max 12.8MB) -> SADDR form.
    uint4 r[11];
    #pragma unroll
    for (int t = 0; t < 11; ++t) {
        const unsigned off = (unsigned)idx[1 + t] * (unsigned)N_DIMS + 16u * g;
        r[t] = *(const uint4*)(Wo8 + off);
    }

    // Pin: loads may not sink below this point.
    __builtin_amdgcn_sched_barrier(0);

    float acc = 0.0f;
    #pragma unroll
    for (int t = 0; t < 11; ++t) {
        float d = dot_row_fp8(a0, a1, a2, a3, r[t]);
        d = group8_reduce(d);
        acc += log_sigmoid_fast(t == 0 ? d : -d);
    }

    __shared__ float sdata[32];
    if (g == 0) sdata[threadIdx.x >> 3] = acc;
    __syncthreads();
    if (threadIdx.x < 32) {
        float s = sdata[threadIdx.x];
        s += __shfl_xor(s, 16);
        s += __shfl_xor(s, 8);
        s += __shfl_xor(s, 4);
        s += __shfl_xor(s, 2);
        s += __shfl_xor(s, 1);
        if (threadIdx.x == 0)
            atomicAdd(out, s * (1.0f / (float)N_SAMPLES));
    }
}

// ---- Fallback fp32 path (R5 kernel) in case ws_size < 12.8 MB -------------
__global__ __launch_bounds__(256, 2) void skipgram_f32_kernel(
        const int* __restrict__ input_idx,
        const int* __restrict__ output_idx,
        const int* __restrict__ neg_idx,
        const float* __restrict__ W_in,
        const float* __restrict__ W_out,
        float* __restrict__ out)
{
    const int g = threadIdx.x & 7;
    const int n = (blockIdx.x * blockDim.x + threadIdx.x) >> 3;

    int idx[12];
    idx[0] = input_idx[n];
    idx[1] = output_idx[n];
    #pragma unroll
    for (int k = 0; k < K_NEG; ++k) idx[2 + k] = neg_idx[n * K_NEG + k];

    const float4* __restrict__ arow = (const float4*)(W_in + (size_t)idx[0] * N_DIMS);
    float4 a0 = arow[0 * 8 + g];
    float4 a1 = arow[1 * 8 + g];
    float4 a2 = arow[2 * 8 + g];
    float4 a3 = arow[3 * 8 + g];

    float4 r[11][4];
    #pragma unroll
    for (int t = 0; t < 11; ++t) {
        const float4* __restrict__ rr =
            (const float4*)(W_out + (size_t)idx[1 + t] * N_DIMS);
        r[t][0] = rr[0 * 8 + g];
        r[t][1] = rr[1 * 8 + g];
        r[t][2] = rr[2 * 8 + g];
        r[t][3] = rr[3 * 8 + g];
    }
    __builtin_amdgcn_sched_barrier(0);

    float acc = 0.0f;
    #pragma unroll
    for (int t = 0; t < 11; ++t) {
        float d = dot4(a0, r[t][0]) + dot4(a1, r[t][1])
                + dot4(a2, r[t][2]) + dot4(a3, r[t][3]);
        d = group8_reduce(d);
        acc += log_sigmoid_fast(t == 0 ? d : -d);
    }

    __shared__ float sdata[32];
    if (g == 0) sdata[threadIdx.x >> 3] = acc;
    __syncthreads();
    if (threadIdx.x < 32) {
        float s = sdata[threadIdx.x];
        s += __shfl_xor(s, 16);
        s += __shfl_xor(s, 8);
        s += __shfl_xor(s, 4);
        s += __shfl_xor(s, 2);
        s += __shfl_xor(s, 1);
        if (threadIdx.x == 0)
            atomicAdd(out, s * (1.0f / (float)N_SAMPLES));
    }
}

extern "C" void kernel_launch(void* const* d_in, const int* in_sizes, int n_in,
                              void* d_out, int out_size, void* d_ws, size_t ws_size,
                              hipStream_t stream) {
    const int*   input_idx  = (const int*)d_in[0];
    const int*   output_idx = (const int*)d_in[1];
    const int*   neg_idx    = (const int*)d_in[2];
    const float* W_in       = (const float*)d_in[3];
    const float* W_out      = (const float*)d_in[4];
    float* out = (float*)d_out;

    const int block = 256;                       // 32 groups of 8 lanes
    const int grid  = N_SAMPLES / (block / 8);   // 2048 blocks, exact cover

    if (ws_size >= WOUT_FP8_BYTES) {
        uint4* Wo8 = (uint4*)d_ws;
        const int ctotal = (int)((size_t)N_WORDS * N_DIMS / 16);  // 800000
        const int cgrid  = (ctotal + 255) / 256;                  // 3125
        convert_fp8_kernel<<<cgrid, 256, 0, stream>>>(W_out, Wo8, out);
        skipgram_fp8_kernel<<<grid, block, 0, stream>>>(
            input_idx, output_idx, neg_idx, W_in,
            (const unsigned char*)Wo8, out);
    } else {
        zero_out_kernel<<<1, 64, 0, stream>>>(out);
        skipgram_f32_kernel<<<grid, block, 0, stream>>>(
            input_idx, output_idx, neg_idx, W_in, W_out, out);
    }
}